// Round 6
// baseline (599.932 us; speedup 1.0000x reference)
//
#include <hip/hip_runtime.h>
#include <hip/hip_bf16.h>
#include <stdint.h>

#define N_ROWS 8192
#define DIM    1024
#define BM 128
#define BN 128
#define BKF 128   // fp8 bytes of K per MFMA
#define NK  (DIM / BKF)   // 8 k-iterations
#define NBLK ((N_ROWS / BM) * (N_ROWS / BN))

typedef float   f32x4  __attribute__((ext_vector_type(4)));
typedef int     i32x4  __attribute__((ext_vector_type(4)));
typedef int     i32x8  __attribute__((ext_vector_type(8)));

// ---------------------------------------------------------------------------
// Kernel 1: fused L2-normalize (fp32 -> fp8 e4m3) + exact fp32 per-row
// diagonal + S zero-init + done-counter reset.
// ---------------------------------------------------------------------------
__global__ __launch_bounds__(256) void nrm_kernel(
    const float* __restrict__ img, const float* __restrict__ txt,
    uint8_t* __restrict__ img_f8, uint8_t* __restrict__ txt_f8,
    float* __restrict__ diag, float* __restrict__ S,
    unsigned* __restrict__ cnt)
{
    const int row  = blockIdx.x;
    const int t    = threadIdx.x;
    const int lane = t & 63;
    const int w    = t >> 6;

    const float4 a = ((const float4*)(img + (size_t)row * DIM))[t];
    const float4 b = ((const float4*)(txt + (size_t)row * DIM))[t];

    float sa = a.x * a.x + a.y * a.y + a.z * a.z + a.w * a.w;
    float sb = b.x * b.x + b.y * b.y + b.z * b.z + b.w * b.w;
#pragma unroll
    for (int d = 1; d < 64; d <<= 1) {
        sa += __shfl_xor(sa, d, 64);
        sb += __shfl_xor(sb, d, 64);
    }
    __shared__ float red[3][4];
    if (lane == 0) { red[0][w] = sa; red[1][w] = sb; }
    __syncthreads();
    sa = red[0][0] + red[0][1] + red[0][2] + red[0][3];
    sb = red[1][0] + red[1][1] + red[1][2] + red[1][3];

    const float ia = 1.0f / fmaxf(sqrtf(sa), 1e-12f);
    const float ib = 1.0f / fmaxf(sqrtf(sb), 1e-12f);

    int ra = 0, rb = 0;
    ra = __builtin_amdgcn_cvt_pk_fp8_f32(a.x * ia, a.y * ia, ra, false);
    ra = __builtin_amdgcn_cvt_pk_fp8_f32(a.z * ia, a.w * ia, ra, true);
    rb = __builtin_amdgcn_cvt_pk_fp8_f32(b.x * ib, b.y * ib, rb, false);
    rb = __builtin_amdgcn_cvt_pk_fp8_f32(b.z * ib, b.w * ib, rb, true);
    ((int*)(img_f8 + (size_t)row * DIM))[t] = ra;
    ((int*)(txt_f8 + (size_t)row * DIM))[t] = rb;

    float dp = (a.x * b.x + a.y * b.y + a.z * b.z + a.w * b.w) * ia * ib;
#pragma unroll
    for (int d = 1; d < 64; d <<= 1) dp += __shfl_xor(dp, d, 64);
    if (lane == 0) red[2][w] = dp;
    __syncthreads();
    if (t == 0) {
        diag[row] = red[2][0] + red[2][1] + red[2][2] + red[2][3];
        S[row] = 0.0f;
        if (row == 0) cnt[0] = 0u;
    }
}

// ---------------------------------------------------------------------------
// Kernel 2: 128x128-tile MX-fp8 GEMM, BARRIER-FREE: no LDS staging at all.
// R4/R5 post-mortem: any LDS K-loop (global_load_lds dbuf OR reg+ds_write)
// gets re-serialized by compiler waitcnt placement -> MfmaUtil 8%. With only
// 8 k-iters the barrier drain dominates. So each wave loads its fragments
// DIRECTLY from global (L2-resident; per-XCD working set ~2.3MB < 4MB L2:
// resident blocks on an XCD share the same B-tile columns since gridDim.x=64
// is a multiple of 8). Fully-unrolled straight-line body, no syncs -> the
// scheduler hoists iter-k+1 loads above iter-k MFMAs freely.
// Fragment (16x16x128 f8f6f4, R3-validated): lane(lr=lane&15, q=lane>>4)
// holds row lr, k = q*32..q*32+31 (two 16B chunks).
// All loads: 8 base pointers + 13-bit immediate offsets (k*128+16 <= 912).
// Fused epilogue: rowsum exp(s-1) -> atomicAdd S[row]; last block reduces.
// ---------------------------------------------------------------------------
__global__ __launch_bounds__(256) void sim_lse_kernel(
    const uint8_t* __restrict__ A, const uint8_t* __restrict__ B,
    float* __restrict__ S, const float* __restrict__ diag,
    unsigned* __restrict__ cnt, float* __restrict__ out)
{
    const int t     = threadIdx.x;
    const int lane  = t & 63;
    const int w     = t >> 6;
    const int waveM = w >> 1;
    const int waveN = w & 1;
    const int lr    = lane & 15;
    const int q     = lane >> 4;

    const int rowA0 = blockIdx.y * BM;
    const int rowB0 = blockIdx.x * BN;

    const uint8_t* pa[4];
    const uint8_t* pb[4];
#pragma unroll
    for (int mi = 0; mi < 4; ++mi)
        pa[mi] = A + (size_t)(rowA0 + waveM * 64 + mi * 16 + lr) * DIM + q * 32;
#pragma unroll
    for (int ni = 0; ni < 4; ++ni)
        pb[ni] = B + (size_t)(rowB0 + waveN * 64 + ni * 16 + lr) * DIM + q * 32;

    f32x4 acc[4][4] = {};

#pragma unroll
    for (int k = 0; k < NK; ++k) {
        const int koff = k * BKF;
        i32x8 af[4], bfr[4];
#pragma unroll
        for (int mi = 0; mi < 4; ++mi) {
            i32x4 lo = *(const i32x4*)(pa[mi] + koff);
            i32x4 hi = *(const i32x4*)(pa[mi] + koff + 16);
            af[mi] = (i32x8){lo.x, lo.y, lo.z, lo.w, hi.x, hi.y, hi.z, hi.w};
        }
#pragma unroll
        for (int ni = 0; ni < 4; ++ni) {
            i32x4 lo = *(const i32x4*)(pb[ni] + koff);
            i32x4 hi = *(const i32x4*)(pb[ni] + koff + 16);
            bfr[ni] = (i32x8){lo.x, lo.y, lo.z, lo.w, hi.x, hi.y, hi.z, hi.w};
        }
#pragma unroll
        for (int mi = 0; mi < 4; ++mi)
#pragma unroll
            for (int ni = 0; ni < 4; ++ni)
                acc[mi][ni] = __builtin_amdgcn_mfma_scale_f32_16x16x128_f8f6f4(
                    af[mi], bfr[ni], acc[mi][ni],
                    0, 0, 0, 127, 0, 127);
    }

    // Epilogue: exp(s-1), sum across 128 columns, atomic into S[row].
    // C/D layout: col = lane&15, row = (lane>>4)*4 + reg
    const float L2E = 1.44269504088896f;
    const int rowbase = rowA0 + waveM * 64;
#pragma unroll
    for (int mi = 0; mi < 4; ++mi) {
        float p0 = 0.f, p1 = 0.f, p2 = 0.f, p3 = 0.f;
#pragma unroll
        for (int ni = 0; ni < 4; ++ni) {
            p0 += exp2f(acc[mi][ni].x * L2E - L2E);
            p1 += exp2f(acc[mi][ni].y * L2E - L2E);
            p2 += exp2f(acc[mi][ni].z * L2E - L2E);
            p3 += exp2f(acc[mi][ni].w * L2E - L2E);
        }
#pragma unroll
        for (int d = 1; d < 16; d <<= 1) {
            p0 += __shfl_xor(p0, d, 64);
            p1 += __shfl_xor(p1, d, 64);
            p2 += __shfl_xor(p2, d, 64);
            p3 += __shfl_xor(p3, d, 64);
        }
        if ((lane & 15) == 0) {
            float* dst = &S[rowbase + mi * 16 + (lane >> 4) * 4];
            atomicAdd(dst + 0, p0);
            atomicAdd(dst + 1, p1);
            atomicAdd(dst + 2, p2);
            atomicAdd(dst + 3, p3);
        }
    }

    // Fused finalization: last block to finish reduces S -> out.
    __threadfence();
    __shared__ bool last;
    if (t == 0) last = (atomicAdd(cnt, 1u) == (unsigned)(NBLK - 1));
    __syncthreads();
    if (last) {
        __threadfence();
        float s = 0.f;
        for (int i = t; i < N_ROWS; i += 256) {
            float Sv = __hip_atomic_load(&S[i], __ATOMIC_RELAXED,
                                         __HIP_MEMORY_SCOPE_AGENT);
            s += logf(Sv) - diag[i];
        }
#pragma unroll
        for (int d = 1; d < 64; d <<= 1) s += __shfl_xor(s, d, 64);
        __shared__ float red[4];
        if ((t & 63) == 0) red[t >> 6] = s;
        __syncthreads();
        if (t == 0)
            out[0] = (red[0] + red[1] + red[2] + red[3]) * (1.0f / N_ROWS);
    }
}

// ---------------------------------------------------------------------------
extern "C" void kernel_launch(void* const* d_in, const int* in_sizes, int n_in,
                              void* d_out, int out_size, void* d_ws, size_t ws_size,
                              hipStream_t stream)
{
    const float* img = (const float*)d_in[0];
    const float* txt = (const float*)d_in[1];
    float* out = (float*)d_out;

    char* ws = (char*)d_ws;
    uint8_t* img_f8 = (uint8_t*)ws;                                  // 8 MiB
    uint8_t* txt_f8 = (uint8_t*)(ws + (size_t)N_ROWS * DIM);         // 8 MiB
    float*   S      = (float*)(ws + (size_t)N_ROWS * DIM * 2);       // 32 KiB
    float*   diag   = S + N_ROWS;                                    // 32 KiB
    unsigned* cnt   = (unsigned*)(diag + N_ROWS);

    nrm_kernel<<<N_ROWS, 256, 0, stream>>>(img, txt, img_f8, txt_f8, diag, S, cnt);
    dim3 grid(N_ROWS / BN, N_ROWS / BM);
    sim_lse_kernel<<<grid, 256, 0, stream>>>(img_f8, txt_f8, S, diag, cnt, out);
}

// Round 7
// 465.764 us; speedup vs baseline: 1.2881x; 1.2881x over previous
//
#include <hip/hip_runtime.h>
#include <hip/hip_bf16.h>
#include <stdint.h>

#define N_ROWS 8192
#define DIM    1024
#define BM 128
#define BN 128
#define BKF 128           // fp8 bytes of K per stage; one MFMA K
#define NK  (DIM / BKF)   // 8 k-iterations
#define MT  4             // M-tiles per block (amortize prologue/epilogue)
#define NBLK ((N_ROWS / BM) * (N_ROWS / BN) / MT)   // 1024 blocks

typedef float   f32x4  __attribute__((ext_vector_type(4)));
typedef int     i32x4  __attribute__((ext_vector_type(4)));
typedef int     i32x8  __attribute__((ext_vector_type(8)));

// ---------------------------------------------------------------------------
// Kernel 1: fused L2-normalize (fp32 -> fp8 e4m3) + exact fp32 per-row
// diagonal + S zero-init + done-counter reset.
// ---------------------------------------------------------------------------
__global__ __launch_bounds__(256) void nrm_kernel(
    const float* __restrict__ img, const float* __restrict__ txt,
    uint8_t* __restrict__ img_f8, uint8_t* __restrict__ txt_f8,
    float* __restrict__ diag, float* __restrict__ S,
    unsigned* __restrict__ cnt)
{
    const int row  = blockIdx.x;
    const int t    = threadIdx.x;
    const int lane = t & 63;
    const int w    = t >> 6;

    const float4 a = ((const float4*)(img + (size_t)row * DIM))[t];
    const float4 b = ((const float4*)(txt + (size_t)row * DIM))[t];

    float sa = a.x * a.x + a.y * a.y + a.z * a.z + a.w * a.w;
    float sb = b.x * b.x + b.y * b.y + b.z * b.z + b.w * b.w;
#pragma unroll
    for (int d = 1; d < 64; d <<= 1) {
        sa += __shfl_xor(sa, d, 64);
        sb += __shfl_xor(sb, d, 64);
    }
    __shared__ float red[3][4];
    if (lane == 0) { red[0][w] = sa; red[1][w] = sb; }
    __syncthreads();
    sa = red[0][0] + red[0][1] + red[0][2] + red[0][3];
    sb = red[1][0] + red[1][1] + red[1][2] + red[1][3];

    const float ia = 1.0f / fmaxf(sqrtf(sa), 1e-12f);
    const float ib = 1.0f / fmaxf(sqrtf(sb), 1e-12f);

    int ra = 0, rb = 0;
    ra = __builtin_amdgcn_cvt_pk_fp8_f32(a.x * ia, a.y * ia, ra, false);
    ra = __builtin_amdgcn_cvt_pk_fp8_f32(a.z * ia, a.w * ia, ra, true);
    rb = __builtin_amdgcn_cvt_pk_fp8_f32(b.x * ib, b.y * ib, rb, false);
    rb = __builtin_amdgcn_cvt_pk_fp8_f32(b.z * ib, b.w * ib, rb, true);
    ((int*)(img_f8 + (size_t)row * DIM))[t] = ra;
    ((int*)(txt_f8 + (size_t)row * DIM))[t] = rb;

    float dp = (a.x * b.x + a.y * b.y + a.z * b.z + a.w * b.w) * ia * ib;
#pragma unroll
    for (int d = 1; d < 64; d <<= 1) dp += __shfl_xor(dp, d, 64);
    if (lane == 0) red[2][w] = dp;
    __syncthreads();
    if (t == 0) {
        diag[row] = red[2][0] + red[2][1] + red[2][2] + red[2][3];
        S[row] = 0.0f;
        if (row == 0) cnt[0] = 0u;
    }
}

// ---------------------------------------------------------------------------
// Kernel 2: MX-fp8 GEMM (K=128 mfma_scale, fmt fp8, scale=1.0), R3 structure
// (single 32KB LDS buffer, global_load_lds width=16, XOR chunk swizzle)
// with TWO R7 changes:
//  (a) each block computes MT=4 M-tiles over the SAME N-column -> 1024 blocks
//      = 4/CU (R3 ran 16/CU; R3 vs m148 showed identical per-iter loop at
//      2x time -> block prologue/epilogue churn, not pipes, was the cost).
//  (b) XCD-clustered swizzle: XCD x owns n-tiles [8x,8x+8) -> its B working
//      set (1 MB) stays resident in its private L2; A streams.
// Fused epilogue: rowsum exp(s-1) -> atomicAdd S[row]; last block reduces.
// ---------------------------------------------------------------------------
__global__ __launch_bounds__(256) void sim_lse_kernel(
    const uint8_t* __restrict__ A, const uint8_t* __restrict__ B,
    float* __restrict__ S, const float* __restrict__ diag,
    unsigned* __restrict__ cnt, float* __restrict__ out)
{
    __shared__ __align__(16) uint8_t As[BM * BKF];   // 16 KiB
    __shared__ __align__(16) uint8_t Bs[BN * BKF];   // 16 KiB

    const int t     = threadIdx.x;
    const int lane  = t & 63;
    const int w     = t >> 6;
    const int waveM = w >> 1;
    const int waveN = w & 1;
    const int lr    = lane & 15;
    const int q     = lane >> 4;              // k-quarter: k = q*32 + j
    const int swz   = lr & 7;
    const int lo_off = (((2 * q) ^ swz) * 16);

    // XCD-aware decomposition: blocks dispatch round-robin over 8 XCDs,
    // so xcd = id&7. XCD x gets n_tiles [8x, 8x+8), all 16 m_groups.
    const int f      = blockIdx.x;
    const int xcd    = f & 7;
    const int slot   = f >> 3;                // 0..127
    const int n_tile = xcd * 8 + (slot & 7);  // 0..63
    const int m_grp  = slot >> 3;             // 0..15

    const int rowB0 = n_tile * BN;
    const uint8_t* Bblk = B + (size_t)rowB0 * DIM;

    // staging geometry (chunk id = is*256 + t; row = chunk>>3, col swizzled)
    const int srow0 = t >> 3;
    const int scol  = t & 7;

    const float L2E = 1.44269504088896f;

    for (int mt = 0; mt < MT; ++mt) {
        const int rowA0 = (m_grp * MT + mt) * BM;
        const uint8_t* Ablk = A + (size_t)rowA0 * DIM;

        f32x4 acc[4][4] = {};

        for (int k0 = 0; k0 < DIM; k0 += BKF) {
            __syncthreads();   // previous tile's readers done; LDS free
#pragma unroll
            for (int is = 0; is < 4; ++is) {
                const int row = is * 32 + srow0;
                const int col = scol ^ (row & 7);
                const uint8_t* ga = Ablk + (size_t)row * DIM + k0 + col * 16;
                const uint8_t* gb = Bblk + (size_t)row * DIM + k0 + col * 16;
                __builtin_amdgcn_global_load_lds(
                    (const __attribute__((address_space(1))) void*)ga,
                    (__attribute__((address_space(3))) void*)&As[(is * 256 + w * 64) * 16],
                    16, 0, 0);
                __builtin_amdgcn_global_load_lds(
                    (const __attribute__((address_space(1))) void*)gb,
                    (__attribute__((address_space(3))) void*)&Bs[(is * 256 + w * 64) * 16],
                    16, 0, 0);
            }
            __syncthreads();   // staging complete

            i32x8 af[4], bfr[4];
#pragma unroll
            for (int mi = 0; mi < 4; ++mi) {
                const uint8_t* base = As + (waveM * 64 + mi * 16 + lr) * BKF;
                i32x4 lo = *(const i32x4*)(base + lo_off);
                i32x4 hi = *(const i32x4*)(base + (lo_off ^ 16));
                af[mi] = (i32x8){lo.x, lo.y, lo.z, lo.w, hi.x, hi.y, hi.z, hi.w};
            }
#pragma unroll
            for (int ni = 0; ni < 4; ++ni) {
                const uint8_t* base = Bs + (waveN * 64 + ni * 16 + lr) * BKF;
                i32x4 lo = *(const i32x4*)(base + lo_off);
                i32x4 hi = *(const i32x4*)(base + (lo_off ^ 16));
                bfr[ni] = (i32x8){lo.x, lo.y, lo.z, lo.w, hi.x, hi.y, hi.z, hi.w};
            }
#pragma unroll
            for (int mi = 0; mi < 4; ++mi)
#pragma unroll
                for (int ni = 0; ni < 4; ++ni)
                    acc[mi][ni] = __builtin_amdgcn_mfma_scale_f32_16x16x128_f8f6f4(
                        af[mi], bfr[ni], acc[mi][ni],
                        0, 0, 0, 127, 0, 127);
        }

        // Epilogue: exp(s-1), sum across 128 columns, atomic into S[row].
        // C/D layout: col = lane&15, row = (lane>>4)*4 + reg
        const int rowbase = rowA0 + waveM * 64;
#pragma unroll
        for (int mi = 0; mi < 4; ++mi) {
            float p0 = 0.f, p1 = 0.f, p2 = 0.f, p3 = 0.f;
#pragma unroll
            for (int ni = 0; ni < 4; ++ni) {
                p0 += exp2f(acc[mi][ni].x * L2E - L2E);
                p1 += exp2f(acc[mi][ni].y * L2E - L2E);
                p2 += exp2f(acc[mi][ni].z * L2E - L2E);
                p3 += exp2f(acc[mi][ni].w * L2E - L2E);
            }
#pragma unroll
            for (int d = 1; d < 16; d <<= 1) {
                p0 += __shfl_xor(p0, d, 64);
                p1 += __shfl_xor(p1, d, 64);
                p2 += __shfl_xor(p2, d, 64);
                p3 += __shfl_xor(p3, d, 64);
            }
            if ((lane & 15) == 0) {
                float* dst = &S[rowbase + mi * 16 + (lane >> 4) * 4];
                atomicAdd(dst + 0, p0);
                atomicAdd(dst + 1, p1);
                atomicAdd(dst + 2, p2);
                atomicAdd(dst + 3, p3);
            }
        }
    }

    // Fused finalization: last block to finish reduces S -> out.
    __threadfence();
    __shared__ bool last;
    if (t == 0) last = (atomicAdd(cnt, 1u) == (unsigned)(NBLK - 1));
    __syncthreads();
    if (last) {
        __threadfence();
        float s = 0.f;
        for (int i = t; i < N_ROWS; i += 256) {
            float Sv = __hip_atomic_load(&S[i], __ATOMIC_RELAXED,
                                         __HIP_MEMORY_SCOPE_AGENT);
            s += logf(Sv) - diag[i];
        }
#pragma unroll
        for (int d = 1; d < 64; d <<= 1) s += __shfl_xor(s, d, 64);
        __shared__ float red[4];
        if ((t & 63) == 0) red[t >> 6] = s;
        __syncthreads();
        if (t == 0)
            out[0] = (red[0] + red[1] + red[2] + red[3]) * (1.0f / N_ROWS);
    }
}

// ---------------------------------------------------------------------------
extern "C" void kernel_launch(void* const* d_in, const int* in_sizes, int n_in,
                              void* d_out, int out_size, void* d_ws, size_t ws_size,
                              hipStream_t stream)
{
    const float* img = (const float*)d_in[0];
    const float* txt = (const float*)d_in[1];
    float* out = (float*)d_out;

    char* ws = (char*)d_ws;
    uint8_t* img_f8 = (uint8_t*)ws;                                  // 8 MiB
    uint8_t* txt_f8 = (uint8_t*)(ws + (size_t)N_ROWS * DIM);         // 8 MiB
    float*   S      = (float*)(ws + (size_t)N_ROWS * DIM * 2);       // 32 KiB
    float*   diag   = S + N_ROWS;                                    // 32 KiB
    unsigned* cnt   = (unsigned*)(diag + N_ROWS);

    nrm_kernel<<<N_ROWS, 256, 0, stream>>>(img, txt, img_f8, txt_f8, diag, S, cnt);
    sim_lse_kernel<<<NBLK, 256, 0, stream>>>(img_f8, txt_f8, S, diag, cnt, out);
}

// Round 8
// 308.368 us; speedup vs baseline: 1.9455x; 1.5104x over previous
//
#include <hip/hip_runtime.h>
#include <hip/hip_bf16.h>
#include <stdint.h>

#define N_ROWS 8192
#define DIM    1024
#define BM 128
#define BN 128
#define BKF 128           // fp8 bytes of K per stage; one MFMA K
#define NK  (DIM / BKF)   // 8 k-iterations
#define MT  4             // M-tiles per block (amortize prologue/epilogue)
#define NBLK ((N_ROWS / BM) * (N_ROWS / BN) / MT)   // 1024 blocks

typedef float   f32x4  __attribute__((ext_vector_type(4)));
typedef int     i32x4  __attribute__((ext_vector_type(4)));
typedef int     i32x8  __attribute__((ext_vector_type(8)));

// ---------------------------------------------------------------------------
// Kernel 1: fused L2-normalize (fp32 -> fp8 e4m3) + exact fp32 per-row
// diagonal + S zero-init + done-counter reset.
// ---------------------------------------------------------------------------
__global__ __launch_bounds__(256) void nrm_kernel(
    const float* __restrict__ img, const float* __restrict__ txt,
    uint8_t* __restrict__ img_f8, uint8_t* __restrict__ txt_f8,
    float* __restrict__ diag, float* __restrict__ S,
    unsigned* __restrict__ cnt)
{
    const int row  = blockIdx.x;
    const int t    = threadIdx.x;
    const int lane = t & 63;
    const int w    = t >> 6;

    const float4 a = ((const float4*)(img + (size_t)row * DIM))[t];
    const float4 b = ((const float4*)(txt + (size_t)row * DIM))[t];

    float sa = a.x * a.x + a.y * a.y + a.z * a.z + a.w * a.w;
    float sb = b.x * b.x + b.y * b.y + b.z * b.z + b.w * b.w;
#pragma unroll
    for (int d = 1; d < 64; d <<= 1) {
        sa += __shfl_xor(sa, d, 64);
        sb += __shfl_xor(sb, d, 64);
    }
    __shared__ float red[3][4];
    if (lane == 0) { red[0][w] = sa; red[1][w] = sb; }
    __syncthreads();
    sa = red[0][0] + red[0][1] + red[0][2] + red[0][3];
    sb = red[1][0] + red[1][1] + red[1][2] + red[1][3];

    const float ia = 1.0f / fmaxf(sqrtf(sa), 1e-12f);
    const float ib = 1.0f / fmaxf(sqrtf(sb), 1e-12f);

    int ra = 0, rb = 0;
    ra = __builtin_amdgcn_cvt_pk_fp8_f32(a.x * ia, a.y * ia, ra, false);
    ra = __builtin_amdgcn_cvt_pk_fp8_f32(a.z * ia, a.w * ia, ra, true);
    rb = __builtin_amdgcn_cvt_pk_fp8_f32(b.x * ib, b.y * ib, rb, false);
    rb = __builtin_amdgcn_cvt_pk_fp8_f32(b.z * ib, b.w * ib, rb, true);
    ((int*)(img_f8 + (size_t)row * DIM))[t] = ra;
    ((int*)(txt_f8 + (size_t)row * DIM))[t] = rb;

    float dp = (a.x * b.x + a.y * b.y + a.z * b.z + a.w * b.w) * ia * ib;
#pragma unroll
    for (int d = 1; d < 64; d <<= 1) dp += __shfl_xor(dp, d, 64);
    if (lane == 0) red[2][w] = dp;
    __syncthreads();
    if (t == 0) {
        diag[row] = red[2][0] + red[2][1] + red[2][2] + red[2][3];
        S[row] = 0.0f;
        if (row == 0) cnt[0] = 0u;
    }
}

// ---------------------------------------------------------------------------
// Kernel 2: MX-fp8 GEMM (K=128 mfma_scale, fmt fp8, scale=1.0), R3 structure
// (single 32KB LDS buffer, global_load_lds width=16, XOR chunk swizzle).
// R7: MT=4 M-tiles per block over the SAME N-column + XCD-clustered swizzle.
// R8 fix: '#pragma unroll 1' on the mt loop. R7's compiler fully unrolled
// mt (trip=4), interleaving 4 K-loops -> 4 live acc sets = 256 VGPR + scratch
// spills (WRITE_SIZE 16->61MB) -> 409us. One acc set live at a time now.
// Fused epilogue: rowsum exp(s-1) -> atomicAdd S[row]; last block reduces.
// ---------------------------------------------------------------------------
__global__ __launch_bounds__(256) void sim_lse_kernel(
    const uint8_t* __restrict__ A, const uint8_t* __restrict__ B,
    float* __restrict__ S, const float* __restrict__ diag,
    unsigned* __restrict__ cnt, float* __restrict__ out)
{
    __shared__ __align__(16) uint8_t As[BM * BKF];   // 16 KiB
    __shared__ __align__(16) uint8_t Bs[BN * BKF];   // 16 KiB

    const int t     = threadIdx.x;
    const int lane  = t & 63;
    const int w     = t >> 6;
    const int waveM = w >> 1;
    const int waveN = w & 1;
    const int lr    = lane & 15;
    const int q     = lane >> 4;              // k-quarter: k = q*32 + j
    const int swz   = lr & 7;
    const int lo_off = (((2 * q) ^ swz) * 16);

    // XCD-aware decomposition: blocks dispatch round-robin over 8 XCDs,
    // so xcd = id&7. XCD x gets n_tiles [8x, 8x+8), all 16 m_groups.
    const int f      = blockIdx.x;
    const int xcd    = f & 7;
    const int slot   = f >> 3;                // 0..127
    const int n_tile = xcd * 8 + (slot & 7);  // 0..63
    const int m_grp  = slot >> 3;             // 0..15

    const int rowB0 = n_tile * BN;
    const uint8_t* Bblk = B + (size_t)rowB0 * DIM;

    // staging geometry (chunk id = is*256 + t; row = chunk>>3, col swizzled)
    const int srow0 = t >> 3;
    const int scol  = t & 7;

    const float L2E = 1.44269504088896f;

#pragma unroll 1   // CRITICAL: R7 regression was compiler unrolling this loop
    for (int mt = 0; mt < MT; ++mt) {
        const int rowA0 = (m_grp * MT + mt) * BM;
        const uint8_t* Ablk = A + (size_t)rowA0 * DIM;

        f32x4 acc[4][4] = {};

#pragma unroll 1
        for (int k0 = 0; k0 < DIM; k0 += BKF) {
            __syncthreads();   // previous tile's readers done; LDS free
#pragma unroll
            for (int is = 0; is < 4; ++is) {
                const int row = is * 32 + srow0;
                const int col = scol ^ (row & 7);
                const uint8_t* ga = Ablk + (size_t)row * DIM + k0 + col * 16;
                const uint8_t* gb = Bblk + (size_t)row * DIM + k0 + col * 16;
                __builtin_amdgcn_global_load_lds(
                    (const __attribute__((address_space(1))) void*)ga,
                    (__attribute__((address_space(3))) void*)&As[(is * 256 + w * 64) * 16],
                    16, 0, 0);
                __builtin_amdgcn_global_load_lds(
                    (const __attribute__((address_space(1))) void*)gb,
                    (__attribute__((address_space(3))) void*)&Bs[(is * 256 + w * 64) * 16],
                    16, 0, 0);
            }
            __syncthreads();   // staging complete

            i32x8 af[4], bfr[4];
#pragma unroll
            for (int mi = 0; mi < 4; ++mi) {
                const uint8_t* base = As + (waveM * 64 + mi * 16 + lr) * BKF;
                i32x4 lo = *(const i32x4*)(base + lo_off);
                i32x4 hi = *(const i32x4*)(base + (lo_off ^ 16));
                af[mi] = (i32x8){lo.x, lo.y, lo.z, lo.w, hi.x, hi.y, hi.z, hi.w};
            }
#pragma unroll
            for (int ni = 0; ni < 4; ++ni) {
                const uint8_t* base = Bs + (waveN * 64 + ni * 16 + lr) * BKF;
                i32x4 lo = *(const i32x4*)(base + lo_off);
                i32x4 hi = *(const i32x4*)(base + (lo_off ^ 16));
                bfr[ni] = (i32x8){lo.x, lo.y, lo.z, lo.w, hi.x, hi.y, hi.z, hi.w};
            }
#pragma unroll
            for (int mi = 0; mi < 4; ++mi)
#pragma unroll
                for (int ni = 0; ni < 4; ++ni)
                    acc[mi][ni] = __builtin_amdgcn_mfma_scale_f32_16x16x128_f8f6f4(
                        af[mi], bfr[ni], acc[mi][ni],
                        0, 0, 0, 127, 0, 127);
        }

        // Epilogue: exp(s-1), sum across 128 columns, atomic into S[row].
        // C/D layout: col = lane&15, row = (lane>>4)*4 + reg
        const int rowbase = rowA0 + waveM * 64;
#pragma unroll
        for (int mi = 0; mi < 4; ++mi) {
            float p0 = 0.f, p1 = 0.f, p2 = 0.f, p3 = 0.f;
#pragma unroll
            for (int ni = 0; ni < 4; ++ni) {
                p0 += exp2f(acc[mi][ni].x * L2E - L2E);
                p1 += exp2f(acc[mi][ni].y * L2E - L2E);
                p2 += exp2f(acc[mi][ni].z * L2E - L2E);
                p3 += exp2f(acc[mi][ni].w * L2E - L2E);
            }
#pragma unroll
            for (int d = 1; d < 16; d <<= 1) {
                p0 += __shfl_xor(p0, d, 64);
                p1 += __shfl_xor(p1, d, 64);
                p2 += __shfl_xor(p2, d, 64);
                p3 += __shfl_xor(p3, d, 64);
            }
            if ((lane & 15) == 0) {
                float* dst = &S[rowbase + mi * 16 + (lane >> 4) * 4];
                atomicAdd(dst + 0, p0);
                atomicAdd(dst + 1, p1);
                atomicAdd(dst + 2, p2);
                atomicAdd(dst + 3, p3);
            }
        }
    }

    // Fused finalization: last block to finish reduces S -> out.
    __threadfence();
    __shared__ bool last;
    if (t == 0) last = (atomicAdd(cnt, 1u) == (unsigned)(NBLK - 1));
    __syncthreads();
    if (last) {
        __threadfence();
        float s = 0.f;
        for (int i = t; i < N_ROWS; i += 256) {
            float Sv = __hip_atomic_load(&S[i], __ATOMIC_RELAXED,
                                         __HIP_MEMORY_SCOPE_AGENT);
            s += logf(Sv) - diag[i];
        }
#pragma unroll
        for (int d = 1; d < 64; d <<= 1) s += __shfl_xor(s, d, 64);
        __shared__ float red[4];
        if ((t & 63) == 0) red[t >> 6] = s;
        __syncthreads();
        if (t == 0)
            out[0] = (red[0] + red[1] + red[2] + red[3]) * (1.0f / N_ROWS);
    }
}

// ---------------------------------------------------------------------------
extern "C" void kernel_launch(void* const* d_in, const int* in_sizes, int n_in,
                              void* d_out, int out_size, void* d_ws, size_t ws_size,
                              hipStream_t stream)
{
    const float* img = (const float*)d_in[0];
    const float* txt = (const float*)d_in[1];
    float* out = (float*)d_out;

    char* ws = (char*)d_ws;
    uint8_t* img_f8 = (uint8_t*)ws;                                  // 8 MiB
    uint8_t* txt_f8 = (uint8_t*)(ws + (size_t)N_ROWS * DIM);         // 8 MiB
    float*   S      = (float*)(ws + (size_t)N_ROWS * DIM * 2);       // 32 KiB
    float*   diag   = S + N_ROWS;                                    // 32 KiB
    unsigned* cnt   = (unsigned*)(diag + N_ROWS);

    nrm_kernel<<<N_ROWS, 256, 0, stream>>>(img, txt, img_f8, txt_f8, diag, S, cnt);
    sim_lse_kernel<<<NBLK, 256, 0, stream>>>(img_f8, txt_f8, S, diag, cnt, out);
}